// Round 1
// 1143.004 us; speedup vs baseline: 1.1534x; 1.1534x over previous
//
#include <hip/hip_runtime.h>
#include <cstdint>
#include <cfloat>
#include <cmath>

typedef unsigned short ushort_t;
typedef short bf16x8 __attribute__((ext_vector_type(8)));
typedef float f32x4 __attribute__((ext_vector_type(4)));

__device__ inline ushort_t f2bf(float f) {
    union { float f; unsigned u; } v; v.f = f;
    return (ushort_t)((v.u + 0x7fffu + ((v.u >> 16) & 1u)) >> 16);   // RNE
}
__device__ inline float bf2f(ushort_t u) {
    union { unsigned u; float f; } v; v.u = ((unsigned)u) << 16;
    return v.f;
}
__device__ inline float bflo_f(unsigned w) { union { unsigned u; float f; } v; v.u = w << 16; return v.f; }
__device__ inline float bfhi_f(unsigned w) { union { unsigned u; float f; } v; v.u = w & 0xFFFF0000u; return v.f; }
__device__ inline unsigned pk2(float a, float b) {
    return (unsigned)f2bf(a) | ((unsigned)f2bf(b) << 16);
}
__device__ inline unsigned relu2(unsigned p) {   // relu two packed bf16
    unsigned lo = (p & 0x8000u) ? 0u : (p & 0xFFFFu);
    unsigned hi = (p & 0x80000000u) ? 0u : (p & 0xFFFF0000u);
    return lo | hi;
}

// ---------------------------------------------------------------------------
// Weight prepack: fp32 OIHW -> bf16 packed-K layout.
// K=32 of the MFMA is packed as [slot s][ci] with slot width cw = 8*ci8.
// kx = g*S + s  (S = 4/ci8 slots per K=32 group), so for ci<=8 one MFMA per ky
// covers all 3 kx taps; for ci=16 two MFMAs per ky; ci=32 -> 3 (unchanged).
// Layout: wp[((ky*G + g)*co + co_i)*32 + k]; out-of-range (kx>=3 or ci pad)
// entries are ZERO so garbage B-operand values are annihilated.
// ---------------------------------------------------------------------------
struct PPJob { const float* src; ushort_t* dst; int ci; int co; int ci8; };
struct PPArgs { PPJob j[15]; };

__global__ __launch_bounds__(256) void prepack_k(PPArgs a) {
    const PPJob p = a.j[blockIdx.x];
    const int G  = (p.ci8 == 1) ? 1 : (p.ci8 == 2) ? 2 : 3;
    const int cw = p.ci8 * 8;          // channels per slot
    const int S  = 4 / p.ci8;          // slots per K=32 group
    const int tot = 3 * G * p.co * 32;
    for (int i = threadIdx.x; i < tot; i += 256) {
        const int k = i & 31;
        const int rest = i >> 5;
        const int co = rest % p.co;
        const int rest2 = rest / p.co;
        const int g = rest2 % G;
        const int ky = rest2 / G;
        const int s = k / cw, cio = k % cw;
        const int kx = g * S + s;
        float v = 0.f;
        if (kx < 3 && cio < p.ci) v = p.src[(co * p.ci + cio) * 9 + ky * 3 + kx];
        p.dst[i] = f2bf(v);
    }
}

// ---------------------------------------------------------------------------
// MFMA implicit-GEMM 3x3 conv, pad 1. NHWC bf16 in/out (or NCHW fp32 in).
// Tile 16x16 pixels per block, 4 waves; wave w computes pixel rows 4w..4w+3.
// MFMA 16x16x32_bf16, A = packed weights (M=16 co), B = input (N=16 px cols).
// K packs kx*ci (see prepack) -> per wave:
//   ci=6  : 12 MFMA, 6 hoisted B-frag reads   (was 36/36)
//   ci=16 : CO=16: 24 MFMA / CO=32: 48 MFMA, 12 hoisted reads (was 36 reads)
//   ci=32 : unchanged 72 MFMA / 18-36 reads
// D layout: pixel = lane&15, co = (lane>>4)*4+reg.
// B-frag of packed layouts reads pixel col+slot -> may overhang to px idx 324
// (the pad slot); it is zeroed so 0-weight x finite = 0 (no NaN).
// ---------------------------------------------------------------------------
template<int CIR, int CO, bool NCHWIN>
__global__ __launch_bounds__(256) void convm_k(
    const void* __restrict__ inv, const ushort_t* __restrict__ wp,
    const float* __restrict__ bias, const ushort_t* __restrict__ skip,
    ushort_t* __restrict__ out, int H, int TX, int relu_in)
{
    constexpr int NT  = CO / 16;
    constexpr int CI8 = (CIR + 7) / 8;                       // 1, 2, 4
    constexpr int G   = (CI8 == 1) ? 1 : (CI8 == 2) ? 2 : 3; // K-groups per ky
    __shared__ __align__(16) ushort_t in_t[18 * 18 * 40 + 64];   // +pad slot 324

    const int n    = blockIdx.y;
    const int tile = blockIdx.x;
    const int ty0  = (tile / TX) * 16, tx0 = (tile % TX) * 16;
    const int tid  = threadIdx.x;
    const int lane = tid & 63, wv = tid >> 6;
    const int col  = lane & 15, oct = lane >> 4;

    // ---- A fragments (packed weights) -> registers ----
    bf16x8 wfrag[3][G][NT];
    #pragma unroll
    for (int ky = 0; ky < 3; ++ky)
        #pragma unroll
        for (int g = 0; g < G; ++g)
            #pragma unroll
            for (int t = 0; t < NT; ++t)
                wfrag[ky][g][t] = *(const bf16x8*)&wp[(((ky * G + g) * CO) + t * 16 + col) * 32 + oct * 8];

    // ---- stage input tile (halo, zero-pad, optional relu) ----
    if constexpr (NCHWIN) {
        // only ch 0..7 are ever read (CI8==1) -> zero just those, incl pad slot
        for (int i = tid; i < 325; i += 256)
            *(uint4*)&in_t[i * 40] = make_uint4(0, 0, 0, 0);
        __syncthreads();
        const float* gin = (const float*)inv;
        constexpr int PR = (CIR + 1) / 2;          // channel pairs
        for (int i = tid; i < PR * 324; i += 256) {
            const int px = i % 324, pr = i / 324;
            const int r = px / 18, c = px % 18;
            const int gy = ty0 - 1 + r, gx = tx0 - 1 + c;
            if ((unsigned)gy < (unsigned)H && (unsigned)gx < (unsigned)H) {
                const size_t b0 = (((size_t)n * CIR + pr * 2) * H + gy) * H + gx;
                const float va = gin[b0];
                const float vb = (pr * 2 + 1 < CIR) ? gin[b0 + (size_t)H * H] : 0.f;
                *(unsigned*)&in_t[px * 40 + pr * 2] = pk2(va, vb);
            }
        }
    } else {
        if (tid < 4) *(uint4*)&in_t[324 * 40 + tid * 8] = make_uint4(0, 0, 0, 0);  // pad slot
        const ushort_t* gin = (const ushort_t*)inv;
        for (int i = tid; i < 324 * CI8; i += 256) {           // stage only real ch groups
            const int px = i / CI8, oc = i % CI8;
            const int r = px / 18, c = px % 18;
            const int gy = ty0 - 1 + r, gx = tx0 - 1 + c;
            uint4 v = make_uint4(0, 0, 0, 0);
            if ((unsigned)gy < (unsigned)H && (unsigned)gx < (unsigned)H) {
                v = *(const uint4*)&gin[(((size_t)n * H + gy) * H + gx) * CIR + oc * 8];
                if (relu_in) { v.x = relu2(v.x); v.y = relu2(v.y); v.z = relu2(v.z); v.w = relu2(v.w); }
            }
            *(uint4*)&in_t[px * 40 + oc * 8] = v;
        }
    }
    __syncthreads();

    // ---- MFMA main loop ----
    f32x4 acc[4][NT];
    #pragma unroll
    for (int r = 0; r < 4; ++r)
        #pragma unroll
        for (int t = 0; t < NT; ++t)
            acc[r][t] = (f32x4){0.f, 0.f, 0.f, 0.f};

    if constexpr (CI8 <= 2) {
        // hoist the 6*G distinct B-fragments (rows wv*4 .. wv*4+5)
        bf16x8 bv[6][G];
        #pragma unroll
        for (int q = 0; q < 6; ++q) {
            const int iy = wv * 4 + q;
            #pragma unroll
            for (int g = 0; g < G; ++g) {
                int pix, cho;
                if constexpr (CI8 == 1) { pix = col + oct;                 cho = 0; }
                else                    { pix = col + g * 2 + (oct >> 1);  cho = (oct & 1) * 8; }
                bv[q][g] = *(const bf16x8*)&in_t[(iy * 18 + pix) * 40 + cho];
            }
        }
        #pragma unroll
        for (int ky = 0; ky < 3; ++ky)
            #pragma unroll
            for (int r = 0; r < 4; ++r)
                #pragma unroll
                for (int g = 0; g < G; ++g)
                    #pragma unroll
                    for (int t = 0; t < NT; ++t)
                        acc[r][t] = __builtin_amdgcn_mfma_f32_16x16x32_bf16(
                            wfrag[ky][g][t], bv[r + ky][g], acc[r][t], 0, 0, 0);
    } else {
        #pragma unroll
        for (int ky = 0; ky < 3; ++ky)
            #pragma unroll
            for (int r = 0; r < 4; ++r) {
                const int iy = wv * 4 + r + ky;
                #pragma unroll
                for (int g = 0; g < 3; ++g) {
                    const bf16x8 b = *(const bf16x8*)&in_t[(iy * 18 + col + g) * 40 + oct * 8];
                    #pragma unroll
                    for (int t = 0; t < NT; ++t)
                        acc[r][t] = __builtin_amdgcn_mfma_f32_16x16x32_bf16(
                            wfrag[ky][g][t], b, acc[r][t], 0, 0, 0);
                }
            }
    }

    // ---- epilogue: bias + optional skip, vectorized bf16 NHWC store ----
    float4 bv4[NT];
    #pragma unroll
    for (int t = 0; t < NT; ++t) bv4[t] = *(const float4*)&bias[t * 16 + oct * 4];
    #pragma unroll
    for (int r = 0; r < 4; ++r) {
        const int gy = ty0 + wv * 4 + r;
        const int gx = tx0 + col;
        const size_t pbase = (((size_t)n * H + gy) * H + gx) * CO + oct * 4;
        #pragma unroll
        for (int t = 0; t < NT; ++t) {
            float v0 = acc[r][t][0] + bv4[t].x;
            float v1 = acc[r][t][1] + bv4[t].y;
            float v2 = acc[r][t][2] + bv4[t].z;
            float v3 = acc[r][t][3] + bv4[t].w;
            if (skip) {
                const uint2 s = *(const uint2*)&skip[pbase + t * 16];
                v0 += bflo_f(s.x); v1 += bfhi_f(s.x);
                v2 += bflo_f(s.y); v3 += bfhi_f(s.y);
            }
            uint2 o;
            o.x = pk2(v0, v1);
            o.y = pk2(v2, v3);
            *(uint2*)&out[pbase + t * 16] = o;
        }
    }
}

// ---------------------------------------------------------------------------
// maxpool 3x3 stride 2 pad 1, NHWC bf16, 8 channels per thread
// ---------------------------------------------------------------------------
__global__ __launch_bounds__(256) void pool_nhwc_k(
    const ushort_t* __restrict__ in, ushort_t* __restrict__ out,
    int NI, int H, int C)
{
    const int HP = H >> 1, C8 = C >> 3;
    const long total = (long)NI * HP * HP * C8;
    long idx = (long)blockIdx.x * 256 + threadIdx.x;
    if (idx >= total) return;
    const int c8 = (int)(idx % C8); long r = idx / C8;
    const int px = (int)(r % HP); r /= HP;
    const int py = (int)(r % HP); const long n = r / HP;
    float m[8];
    #pragma unroll
    for (int k = 0; k < 8; ++k) m[k] = -FLT_MAX;
    for (int dy = 0; dy < 3; ++dy) {
        const int y = 2 * py - 1 + dy;
        if ((unsigned)y >= (unsigned)H) continue;
        for (int dx = 0; dx < 3; ++dx) {
            const int x = 2 * px - 1 + dx;
            if ((unsigned)x >= (unsigned)H) continue;
            const uint4 v = *(const uint4*)&in[(((long)n * H + y) * H + x) * C + c8 * 8];
            m[0] = fmaxf(m[0], bflo_f(v.x)); m[1] = fmaxf(m[1], bfhi_f(v.x));
            m[2] = fmaxf(m[2], bflo_f(v.y)); m[3] = fmaxf(m[3], bfhi_f(v.y));
            m[4] = fmaxf(m[4], bflo_f(v.z)); m[5] = fmaxf(m[5], bfhi_f(v.z));
            m[6] = fmaxf(m[6], bflo_f(v.w)); m[7] = fmaxf(m[7], bfhi_f(v.w));
        }
    }
    uint4 o;
    o.x = (unsigned)f2bf(m[0]) | ((unsigned)f2bf(m[1]) << 16);
    o.y = (unsigned)f2bf(m[2]) | ((unsigned)f2bf(m[3]) << 16);
    o.z = (unsigned)f2bf(m[4]) | ((unsigned)f2bf(m[5]) << 16);
    o.w = (unsigned)f2bf(m[6]) | ((unsigned)f2bf(m[7]) << 16);
    *(uint4*)&out[(((long)n * HP + py) * HP + px) * C + c8 * 8] = o;
}

// ---------------------------------------------------------------------------
// Split-K GEMM + reduce (fp32, unchanged)
// ---------------------------------------------------------------------------
__global__ __launch_bounds__(256) void gemm_splitk_k(
    const float* __restrict__ A, const float* __restrict__ B,
    float* __restrict__ partial, int M, int N, int K, int KC)
{
    __shared__ __align__(16) float As[32][65];
    __shared__ __align__(16) float Bs[32][65];
    const int m0 = blockIdx.x * 64, n0 = blockIdx.y * 64;
    const int kbase = blockIdx.z * KC;
    const int tid = threadIdx.x;
    const int tx = tid & 15, ty = tid >> 4;

    float acc[4][4];
    #pragma unroll
    for (int i = 0; i < 4; ++i)
        #pragma unroll
        for (int j = 0; j < 4; ++j) acc[i][j] = 0.f;

    for (int k0 = kbase; k0 < kbase + KC; k0 += 32) {
        for (int i = tid; i < 64 * 32; i += 256) {
            const int m = i >> 5, k = i & 31;
            As[k][m] = A[(size_t)(m0 + m) * K + k0 + k];
        }
        for (int i = tid; i < 64 * 32; i += 256) {
            const int nn = i >> 5, k = i & 31;
            Bs[k][nn] = B[(size_t)(n0 + nn) * K + k0 + k];
        }
        __syncthreads();
        #pragma unroll
        for (int k = 0; k < 32; ++k) {
            const float4 a = *(const float4*)&As[k][ty * 4];
            const float4 b = *(const float4*)&Bs[k][tx * 4];
            acc[0][0] = fmaf(a.x, b.x, acc[0][0]);
            acc[0][1] = fmaf(a.x, b.y, acc[0][1]);
            acc[0][2] = fmaf(a.x, b.z, acc[0][2]);
            acc[0][3] = fmaf(a.x, b.w, acc[0][3]);
            acc[1][0] = fmaf(a.y, b.x, acc[1][0]);
            acc[1][1] = fmaf(a.y, b.y, acc[1][1]);
            acc[1][2] = fmaf(a.y, b.z, acc[1][2]);
            acc[1][3] = fmaf(a.y, b.w, acc[1][3]);
            acc[2][0] = fmaf(a.z, b.x, acc[2][0]);
            acc[2][1] = fmaf(a.z, b.y, acc[2][1]);
            acc[2][2] = fmaf(a.z, b.z, acc[2][2]);
            acc[2][3] = fmaf(a.z, b.w, acc[2][3]);
            acc[3][0] = fmaf(a.w, b.x, acc[3][0]);
            acc[3][1] = fmaf(a.w, b.y, acc[3][1]);
            acc[3][2] = fmaf(a.w, b.z, acc[3][2]);
            acc[3][3] = fmaf(a.w, b.w, acc[3][3]);
        }
        __syncthreads();
    }

    float* pbase = partial + (size_t)blockIdx.z * M * N;
    #pragma unroll
    for (int i = 0; i < 4; ++i) {
        float4 o = make_float4(acc[i][0], acc[i][1], acc[i][2], acc[i][3]);
        *(float4*)&pbase[(size_t)(m0 + ty * 4 + i) * N + n0 + tx * 4] = o;
    }
}

__global__ __launch_bounds__(256) void gemm_reduce_k(
    const float* __restrict__ partial, const float* __restrict__ bias,
    float* __restrict__ out, int MN, int N, int S, int relu)
{
    const int idx = blockIdx.x * 256 + threadIdx.x;
    if (idx >= MN) return;
    float s = bias[idx % N];
    for (int i = 0; i < S; ++i) s += partial[(size_t)i * MN + idx];
    if (relu) s = fmaxf(s, 0.f);
    out[idx] = s;
}

// ---------------------------------------------------------------------------
// CBAM (leading relu): input NHWC bf16, output NCHW fp32  (unchanged)
// ---------------------------------------------------------------------------
__global__ __launch_bounds__(256) void cbam_k(
    const ushort_t* __restrict__ in, const float* __restrict__ fc1,
    const float* __restrict__ fc2, const float* __restrict__ spw,
    float* __restrict__ out)
{
    __shared__ float xl[32][257];
    __shared__ float cmean[32], cmax[32], hidm[8], hidx[8], ca[32];
    __shared__ float spm[256], spx[256], sa[256];
    const int n = blockIdx.x, tid = threadIdx.x;
    const ushort_t* inN = in + (size_t)n * 8192;
    #pragma unroll
    for (int c8 = 0; c8 < 4; ++c8) {
        const uint4 v = *(const uint4*)&inN[tid * 32 + c8 * 8];
        xl[c8 * 8 + 0][tid] = fmaxf(bflo_f(v.x), 0.f);
        xl[c8 * 8 + 1][tid] = fmaxf(bfhi_f(v.x), 0.f);
        xl[c8 * 8 + 2][tid] = fmaxf(bflo_f(v.y), 0.f);
        xl[c8 * 8 + 3][tid] = fmaxf(bfhi_f(v.y), 0.f);
        xl[c8 * 8 + 4][tid] = fmaxf(bflo_f(v.z), 0.f);
        xl[c8 * 8 + 5][tid] = fmaxf(bfhi_f(v.z), 0.f);
        xl[c8 * 8 + 6][tid] = fmaxf(bflo_f(v.w), 0.f);
        xl[c8 * 8 + 7][tid] = fmaxf(bfhi_f(v.w), 0.f);
    }
    __syncthreads();
    if (tid < 32) {
        float s = 0.f, m = -FLT_MAX;
        for (int p = 0; p < 256; ++p) { float v = xl[tid][p]; s += v; m = fmaxf(m, v); }
        cmean[tid] = s * (1.f / 256.f); cmax[tid] = m;
    }
    __syncthreads();
    if (tid < 8) {
        float sm = 0.f, sx = 0.f;
        for (int c = 0; c < 32; ++c) {
            float f = fc1[tid * 32 + c];
            sm += f * cmean[c]; sx += f * cmax[c];
        }
        hidm[tid] = fmaxf(sm, 0.f); hidx[tid] = fmaxf(sx, 0.f);
    }
    __syncthreads();
    if (tid < 32) {
        float s = 0.f;
        for (int h = 0; h < 8; ++h) s += fc2[tid * 8 + h] * (hidm[h] + hidx[h]);
        ca[tid] = 1.f / (1.f + expf(-s));
    }
    __syncthreads();
    {
        float s = 0.f, m = -FLT_MAX;
        for (int c = 0; c < 32; ++c) {
            float v = xl[c][tid] * ca[c];
            xl[c][tid] = v;
            s += v; m = fmaxf(m, v);
        }
        spm[tid] = s * (1.f / 32.f); spx[tid] = m;
    }
    __syncthreads();
    {
        const int y = tid >> 4, x = tid & 15;
        float s = 0.f;
        for (int ky = 0; ky < 7; ++ky) {
            const int yy = y + ky - 3;
            if (yy < 0 || yy >= 16) continue;
            for (int kx = 0; kx < 7; ++kx) {
                const int xx = x + kx - 3;
                if (xx < 0 || xx >= 16) continue;
                const int p = yy * 16 + xx;
                s += spm[p] * spw[ky * 7 + kx] + spx[p] * spw[49 + ky * 7 + kx];
            }
        }
        sa[tid] = 1.f / (1.f + expf(-s));
    }
    __syncthreads();
    float* outN = out + (size_t)n * 8192;
    const float sav = sa[tid];
    for (int c = 0; c < 32; ++c) outN[c * 256 + tid] = xl[c][tid] * sav;
}

// ---------------------------------------------------------------------------
// GRU scan (unchanged)
// ---------------------------------------------------------------------------
__global__ __launch_bounds__(384) void gru_k(
    const float* __restrict__ gi, const float* __restrict__ done,
    const float* __restrict__ h0, const float* __restrict__ whh,
    const float* __restrict__ bhh, float* __restrict__ hidden)
{
    const int b = blockIdx.x, j = threadIdx.x;
    __shared__ __align__(16) float hl[128];
    __shared__ float gh[384];
    float4 wr[32];
    const float4* wrow = (const float4*)(whh + (size_t)j * 128);
    #pragma unroll
    for (int i = 0; i < 32; ++i) wr[i] = wrow[i];
    const float bj = bhh[j];
    if (j < 128) hl[j] = h0[b * 128 + j];
    __syncthreads();
    for (int t = 0; t < 64; ++t) {
        const int rowi = t * 8 + b;
        const float dmask = 1.f - done[rowi];
        if (j < 128) hl[j] *= dmask;
        __syncthreads();
        float s = bj;
        const float4* h4 = (const float4*)hl;
        #pragma unroll
        for (int i = 0; i < 32; ++i) {
            const float4 h = h4[i];
            s = fmaf(wr[i].x, h.x, s);
            s = fmaf(wr[i].y, h.y, s);
            s = fmaf(wr[i].z, h.z, s);
            s = fmaf(wr[i].w, h.w, s);
        }
        gh[j] = s;
        __syncthreads();
        if (j < 128) {
            const float* gir = gi + (size_t)rowi * 384;
            const float r = 1.f / (1.f + expf(-(gir[j] + gh[j])));
            const float z = 1.f / (1.f + expf(-(gir[128 + j] + gh[128 + j])));
            const float nn = tanhf(gir[256 + j] + r * gh[256 + j]);
            const float hm = hl[j];
            const float hn = (1.f - z) * nn + z * hm;
            hl[j] = hn;
            hidden[(size_t)rowi * 128 + j] = hn;
        }
        __syncthreads();
    }
}

// ---------------------------------------------------------------------------
// actor/critic heads (unchanged)
// ---------------------------------------------------------------------------
__global__ __launch_bounds__(256) void heads_k(
    const float* __restrict__ hidden, const float* __restrict__ aw,
    const float* __restrict__ ab, const float* __restrict__ cw,
    const float* __restrict__ cb, float* __restrict__ out)
{
    const int idx = blockIdx.x * 256 + threadIdx.x;  // 2048
    const int m = idx >> 2, c = idx & 3;
    const float* h = hidden + (size_t)m * 128;
    const float* w = (c < 3) ? (aw + (size_t)c * 128) : cw;
    float s = (c < 3) ? ab[c] : cb[0];
    for (int k = 0; k < 128; ++k) s = fmaf(h[k], w[k], s);
    out[idx] = s;
}

// ---------------------------------------------------------------------------
extern "C" void kernel_launch(void* const* d_in, const int* in_sizes, int n_in,
                              void* d_out, int out_size, void* d_ws, size_t ws_size,
                              hipStream_t stream)
{
    const float* x      = (const float*)d_in[0];
    const float* done   = (const float*)d_in[1];
    const float* gstate = (const float*)d_in[2];
    const float* s0_cw  = (const float*)d_in[3];
    const float* s0_cb  = (const float*)d_in[4];
    const float* s0_rw  = (const float*)d_in[5];
    const float* s0_rb  = (const float*)d_in[6];
    const float* s1_cw  = (const float*)d_in[7];
    const float* s1_cb  = (const float*)d_in[8];
    const float* s1_rw  = (const float*)d_in[9];
    const float* s1_rb  = (const float*)d_in[10];
    const float* s2_cw  = (const float*)d_in[11];
    const float* s2_cb  = (const float*)d_in[12];
    const float* s2_rw  = (const float*)d_in[13];
    const float* s2_rb  = (const float*)d_in[14];
    const float* cfc1   = (const float*)d_in[15];
    const float* cfc2   = (const float*)d_in[16];
    const float* cspw   = (const float*)d_in[17];
    const float* fc_w   = (const float*)d_in[18];
    const float* fc_b   = (const float*)d_in[19];
    const float* gwih   = (const float*)d_in[20];
    const float* gwhh   = (const float*)d_in[21];
    const float* gbih   = (const float*)d_in[22];
    const float* gbhh   = (const float*)d_in[23];
    const float* aw     = (const float*)d_in[24];
    const float* ab     = (const float*)d_in[25];
    const float* cwt    = (const float*)d_in[26];
    const float* cbs    = (const float*)d_in[27];
    float* out = (float*)d_out;

    // ---- ws layout (ushort units); peak ~176.4 MB ----
    ushort_t* wsu = (ushort_t*)d_ws;
    ushort_t* SCR = wsu;                       // 33,554,432 u (67.1 MB) scratch/tmp
    ushort_t* U1  = wsu + 33554432;            // 33,554,432 u (67.1 MB) s0 x
    ushort_t* U3  = wsu + 67108864;            // 16,777,216 u (33.5 MB) s1 x
    ushort_t* X0  = wsu + 83886080;            //  4,194,304 u ( 8.4 MB) s2 x
    ushort_t* WP  = wsu + 88080384;            //    131,072 u  weights
    // fp32 misc (placed in U1 region, free by FC time); CBO in SCR region
    float* CBO   = (float*)SCR;                // 4,194,304 f
    float* PART  = (float*)U1;                 // 4,194,304 f
    float* FEAT  = PART + 4194304;             //   131,072 f
    float* GI    = FEAT + 131072;              //   196,608 f
    float* PARTG = GI + 196608;                //   786,432 f
    float* HID   = PARTG + 786432;             //    65,536 f

    // ---- prepack all 15 conv weight tensors (packed-K layout) ----
    // sizes: ci8=1: 3*1*co*32 ; ci8=2: 3*2*co*32 ; ci8=4: 3*3*co*32
    ushort_t* wp_s0e = WP;                       // 1536
    ushort_t* wp_s0r = WP + 1536;                // 4 x 3072
    ushort_t* wp_s1e = WP + 13824;               // 6144
    ushort_t* wp_s1r = WP + 19968;               // 4 x 9216
    ushort_t* wp_s2e = WP + 56832;               // 9216
    ushort_t* wp_s2r = WP + 66048;               // 4 x 9216 -> end 102912
    {
        PPArgs a;
        a.j[0] = {s0_cw, wp_s0e, 6, 16, 1};
        for (int i = 0; i < 4; ++i) a.j[1 + i] = {s0_rw + i * 2304, wp_s0r + i * 3072, 16, 16, 2};
        a.j[5] = {s1_cw, wp_s1e, 16, 32, 2};
        for (int i = 0; i < 4; ++i) a.j[6 + i] = {s1_rw + i * 9216, wp_s1r + i * 9216, 32, 32, 4};
        a.j[10] = {s2_cw, wp_s2e, 32, 32, 4};
        for (int i = 0; i < 4; ++i) a.j[11 + i] = {s2_rw + i * 9216, wp_s2r + i * 9216, 32, 32, 4};
        prepack_k<<<15, 256, 0, stream>>>(a);
    }

    // ---- stage 0: entry conv (6->16 @128) + pool, 4 chunks of 128 images ----
    for (int c = 0; c < 4; ++c) {
        const float* xin = x + (size_t)c * 128 * 6 * 128 * 128;
        convm_k<6, 16, true><<<dim3(64, 128), 256, 0, stream>>>(
            xin, wp_s0e, s0_cb, nullptr, SCR, 128, 8, 0);
        pool_nhwc_k<<<4096, 256, 0, stream>>>(SCR, U1 + (size_t)c * 8388608, 128, 128, 16);
    }
    // ---- stage 0 resblocks (16ch @64) ----
    convm_k<16, 16, false><<<dim3(16, 512), 256, 0, stream>>>(U1,  wp_s0r + 0 * 3072, s0_rb + 0,  nullptr, SCR, 64, 4, 1);
    convm_k<16, 16, false><<<dim3(16, 512), 256, 0, stream>>>(SCR, wp_s0r + 1 * 3072, s0_rb + 16, U1,      U1,  64, 4, 1);
    convm_k<16, 16, false><<<dim3(16, 512), 256, 0, stream>>>(U1,  wp_s0r + 2 * 3072, s0_rb + 32, nullptr, SCR, 64, 4, 1);
    convm_k<16, 16, false><<<dim3(16, 512), 256, 0, stream>>>(SCR, wp_s0r + 3 * 3072, s0_rb + 48, U1,      U1,  64, 4, 1);
    // ---- stage 1: entry conv (16->32 @64) + pool, 2 chunks of 256 images ----
    for (int c = 0; c < 2; ++c) {
        convm_k<16, 32, false><<<dim3(16, 256), 256, 0, stream>>>(
            U1 + (size_t)c * 16777216, wp_s1e, s1_cb, nullptr, SCR, 64, 4, 0);
        pool_nhwc_k<<<4096, 256, 0, stream>>>(SCR, U3 + (size_t)c * 8388608, 256, 64, 32);
    }
    // ---- stage 1 resblocks (32ch @32) ----
    convm_k<32, 32, false><<<dim3(4, 512), 256, 0, stream>>>(U3,  wp_s1r + 0 * 9216, s1_rb + 0,  nullptr, SCR, 32, 2, 1);
    convm_k<32, 32, false><<<dim3(4, 512), 256, 0, stream>>>(SCR, wp_s1r + 1 * 9216, s1_rb + 32, U3,      U3,  32, 2, 1);
    convm_k<32, 32, false><<<dim3(4, 512), 256, 0, stream>>>(U3,  wp_s1r + 2 * 9216, s1_rb + 64, nullptr, SCR, 32, 2, 1);
    convm_k<32, 32, false><<<dim3(4, 512), 256, 0, stream>>>(SCR, wp_s1r + 3 * 9216, s1_rb + 96, U3,      U3,  32, 2, 1);
    // ---- stage 2: entry conv (32->32 @32) + pool ----
    convm_k<32, 32, false><<<dim3(4, 512), 256, 0, stream>>>(U3, wp_s2e, s2_cb, nullptr, SCR, 32, 2, 0);
    pool_nhwc_k<<<2048, 256, 0, stream>>>(SCR, X0, 512, 32, 32);
    // ---- stage 2 resblocks (32ch @16) ----
    convm_k<32, 32, false><<<dim3(1, 512), 256, 0, stream>>>(X0,  wp_s2r + 0 * 9216, s2_rb + 0,  nullptr, SCR, 16, 1, 1);
    convm_k<32, 32, false><<<dim3(1, 512), 256, 0, stream>>>(SCR, wp_s2r + 1 * 9216, s2_rb + 32, X0,      X0,  16, 1, 1);
    convm_k<32, 32, false><<<dim3(1, 512), 256, 0, stream>>>(X0,  wp_s2r + 2 * 9216, s2_rb + 64, nullptr, SCR, 16, 1, 1);
    convm_k<32, 32, false><<<dim3(1, 512), 256, 0, stream>>>(SCR, wp_s2r + 3 * 9216, s2_rb + 96, X0,      X0,  16, 1, 1);
    // ---- relu + CBAM (NHWC bf16 -> NCHW fp32) ----
    cbam_k<<<512, 256, 0, stream>>>(X0, cfc1, cfc2, cspw, CBO);
    // ---- FC 8192->256 (+relu), split-K=32 ----
    gemm_splitk_k<<<dim3(8, 4, 32), 256, 0, stream>>>(CBO, fc_w, PART, 512, 256, 8192, 256);
    gemm_reduce_k<<<512, 256, 0, stream>>>(PART, fc_b, FEAT, 512 * 256, 256, 32, 1);
    // ---- gi = feat @ Wih^T + bih, split-K=4 ----
    gemm_splitk_k<<<dim3(8, 6, 4), 256, 0, stream>>>(FEAT, gwih, PARTG, 512, 384, 256, 64);
    gemm_reduce_k<<<768, 256, 0, stream>>>(PARTG, gbih, GI, 512 * 384, 384, 4, 0);
    // ---- GRU scan ----
    gru_k<<<8, 384, 0, stream>>>(GI, done, gstate, gwhh, gbhh, HID);
    // ---- heads ----
    heads_k<<<8, 256, 0, stream>>>(HID, aw, ab, cwt, cbs, out);
}

// Round 2
// 1086.874 us; speedup vs baseline: 1.2129x; 1.0516x over previous
//
#include <hip/hip_runtime.h>
#include <cstdint>
#include <cfloat>
#include <cmath>

typedef unsigned short ushort_t;
typedef short bf16x8 __attribute__((ext_vector_type(8)));
typedef float f32x4 __attribute__((ext_vector_type(4)));

__device__ inline ushort_t f2bf(float f) {
    union { float f; unsigned u; } v; v.f = f;
    return (ushort_t)((v.u + 0x7fffu + ((v.u >> 16) & 1u)) >> 16);   // RNE
}
__device__ inline float bf2f(ushort_t u) {
    union { unsigned u; float f; } v; v.u = ((unsigned)u) << 16;
    return v.f;
}
__device__ inline float bflo_f(unsigned w) { union { unsigned u; float f; } v; v.u = w << 16; return v.f; }
__device__ inline float bfhi_f(unsigned w) { union { unsigned u; float f; } v; v.u = w & 0xFFFF0000u; return v.f; }
__device__ inline unsigned pk2(float a, float b) {
    return (unsigned)f2bf(a) | ((unsigned)f2bf(b) << 16);
}
__device__ inline unsigned relu2(unsigned p) {   // relu two packed bf16
    unsigned lo = (p & 0x8000u) ? 0u : (p & 0xFFFFu);
    unsigned hi = (p & 0x80000000u) ? 0u : (p & 0xFFFF0000u);
    return lo | hi;
}

// ---------------------------------------------------------------------------
// Weight prepack: fp32 OIHW -> bf16 packed-K layout.
// K=32 of the MFMA is packed as [slot s][ci] with slot width cw = 8*ci8.
// kx = g*S + s  (S = 4/ci8 slots per K=32 group), so for ci<=8 one MFMA per ky
// covers all 3 kx taps; for ci=16 two MFMAs per ky; ci=32 -> 3 (unchanged).
// Out-of-range (kx>=3 or ci pad) entries are ZERO.
// ---------------------------------------------------------------------------
struct PPJob { const float* src; ushort_t* dst; int ci; int co; int ci8; };
struct PPArgs { PPJob j[15]; };

__global__ __launch_bounds__(256) void prepack_k(PPArgs a) {
    const PPJob p = a.j[blockIdx.x];
    const int G  = (p.ci8 == 1) ? 1 : (p.ci8 == 2) ? 2 : 3;
    const int cw = p.ci8 * 8;          // channels per slot
    const int S  = 4 / p.ci8;          // slots per K=32 group
    const int tot = 3 * G * p.co * 32;
    for (int i = threadIdx.x; i < tot; i += 256) {
        const int k = i & 31;
        const int rest = i >> 5;
        const int co = rest % p.co;
        const int rest2 = rest / p.co;
        const int g = rest2 % G;
        const int ky = rest2 / G;
        const int s = k / cw, cio = k % cw;
        const int kx = g * S + s;
        float v = 0.f;
        if (kx < 3 && cio < p.ci) v = p.src[(co * p.ci + cio) * 9 + ky * 3 + kx];
        p.dst[i] = f2bf(v);
    }
}

// ---------------------------------------------------------------------------
// MFMA implicit-GEMM 3x3 conv, pad 1. NHWC bf16 in/out (or NCHW fp32 in).
// Tile 16x16 pixels per block, 4 waves; wave w computes pixel rows 4w..4w+3.
// MFMA 16x16x32_bf16, A = packed weights (M=16 co), B = input (N=16 px cols).
// D layout: pixel = lane&15, co = (lane>>4)*4+reg.
//
// POOL=true (entry convs): tiles OVERLAP with stride 14 (ty0=min(14b,H-16));
// each block fully owns pool rows [ty0/2+1, ty0/2+7] (row 0 on edge tiles via
// padding), so maxpool 3x3/s2 is computed in-block from the conv tile staged
// in LDS (reusing in_t) and only pooled NHWC bf16 is written. Overlapping
// tiles rewrite identical values (max/round commute) - benign.
// ---------------------------------------------------------------------------
template<int CIR, int CO, bool NCHWIN, bool POOL>
__global__ __launch_bounds__(256) void convm_k(
    const void* __restrict__ inv, const ushort_t* __restrict__ wp,
    const float* __restrict__ bias, const ushort_t* __restrict__ skip,
    ushort_t* __restrict__ out, int H, int TX, int relu_in)
{
    constexpr int NT  = CO / 16;
    constexpr int CI8 = (CIR + 7) / 8;                       // 1, 2, 4
    constexpr int G   = (CI8 == 1) ? 1 : (CI8 == 2) ? 2 : 3; // K-groups per ky
    __shared__ __align__(16) ushort_t in_t[18 * 18 * 40 + 64];   // +pad slot 324

    const int n    = blockIdx.y;
    const int tile = blockIdx.x;
    int ty0, tx0;
    if constexpr (POOL) {
        ty0 = (tile / TX) * 14; if (ty0 > H - 16) ty0 = H - 16;
        tx0 = (tile % TX) * 14; if (tx0 > H - 16) tx0 = H - 16;
    } else {
        ty0 = (tile / TX) * 16; tx0 = (tile % TX) * 16;
    }
    const int tid  = threadIdx.x;
    const int lane = tid & 63, wv = tid >> 6;
    const int col  = lane & 15, oct = lane >> 4;

    // ---- A fragments (packed weights) -> registers ----
    bf16x8 wfrag[3][G][NT];
    #pragma unroll
    for (int ky = 0; ky < 3; ++ky)
        #pragma unroll
        for (int g = 0; g < G; ++g)
            #pragma unroll
            for (int t = 0; t < NT; ++t)
                wfrag[ky][g][t] = *(const bf16x8*)&wp[(((ky * G + g) * CO) + t * 16 + col) * 32 + oct * 8];

    // ---- stage input tile (halo, zero-pad, optional relu) ----
    if constexpr (NCHWIN) {
        // only ch 0..7 are ever read (CI8==1) -> zero just those, incl pad slot
        for (int i = tid; i < 325; i += 256)
            *(uint4*)&in_t[i * 40] = make_uint4(0, 0, 0, 0);
        __syncthreads();
        const float* gin = (const float*)inv;
        constexpr int PR = (CIR + 1) / 2;          // channel pairs
        for (int i = tid; i < PR * 324; i += 256) {
            const int px = i % 324, pr = i / 324;
            const int r = px / 18, c = px % 18;
            const int gy = ty0 - 1 + r, gx = tx0 - 1 + c;
            if ((unsigned)gy < (unsigned)H && (unsigned)gx < (unsigned)H) {
                const size_t b0 = (((size_t)n * CIR + pr * 2) * H + gy) * H + gx;
                const float va = gin[b0];
                const float vb = (pr * 2 + 1 < CIR) ? gin[b0 + (size_t)H * H] : 0.f;
                *(unsigned*)&in_t[px * 40 + pr * 2] = pk2(va, vb);
            }
        }
    } else {
        if (tid < 4) *(uint4*)&in_t[324 * 40 + tid * 8] = make_uint4(0, 0, 0, 0);  // pad slot
        const ushort_t* gin = (const ushort_t*)inv;
        for (int i = tid; i < 324 * CI8; i += 256) {           // stage only real ch groups
            const int px = i / CI8, oc = i % CI8;
            const int r = px / 18, c = px % 18;
            const int gy = ty0 - 1 + r, gx = tx0 - 1 + c;
            uint4 v = make_uint4(0, 0, 0, 0);
            if ((unsigned)gy < (unsigned)H && (unsigned)gx < (unsigned)H) {
                v = *(const uint4*)&gin[(((size_t)n * H + gy) * H + gx) * CIR + oc * 8];
                if (relu_in) { v.x = relu2(v.x); v.y = relu2(v.y); v.z = relu2(v.z); v.w = relu2(v.w); }
            }
            *(uint4*)&in_t[px * 40 + oc * 8] = v;
        }
    }
    __syncthreads();

    // ---- MFMA main loop ----
    f32x4 acc[4][NT];
    #pragma unroll
    for (int r = 0; r < 4; ++r)
        #pragma unroll
        for (int t = 0; t < NT; ++t)
            acc[r][t] = (f32x4){0.f, 0.f, 0.f, 0.f};

    if constexpr (CI8 <= 2) {
        // hoist the 6*G distinct B-fragments (rows wv*4 .. wv*4+5)
        bf16x8 bv[6][G];
        #pragma unroll
        for (int q = 0; q < 6; ++q) {
            const int iy = wv * 4 + q;
            #pragma unroll
            for (int g = 0; g < G; ++g) {
                int pix, cho;
                if constexpr (CI8 == 1) { pix = col + oct;                 cho = 0; }
                else                    { pix = col + g * 2 + (oct >> 1);  cho = (oct & 1) * 8; }
                bv[q][g] = *(const bf16x8*)&in_t[(iy * 18 + pix) * 40 + cho];
            }
        }
        #pragma unroll
        for (int ky = 0; ky < 3; ++ky)
            #pragma unroll
            for (int r = 0; r < 4; ++r)
                #pragma unroll
                for (int g = 0; g < G; ++g)
                    #pragma unroll
                    for (int t = 0; t < NT; ++t)
                        acc[r][t] = __builtin_amdgcn_mfma_f32_16x16x32_bf16(
                            wfrag[ky][g][t], bv[r + ky][g], acc[r][t], 0, 0, 0);
    } else {
        #pragma unroll
        for (int ky = 0; ky < 3; ++ky)
            #pragma unroll
            for (int r = 0; r < 4; ++r) {
                const int iy = wv * 4 + r + ky;
                #pragma unroll
                for (int g = 0; g < 3; ++g) {
                    const bf16x8 b = *(const bf16x8*)&in_t[(iy * 18 + col + g) * 40 + oct * 8];
                    #pragma unroll
                    for (int t = 0; t < NT; ++t)
                        acc[r][t] = __builtin_amdgcn_mfma_f32_16x16x32_bf16(
                            wfrag[ky][g][t], b, acc[r][t], 0, 0, 0);
                }
            }
    }

    // ---- epilogue ----
    float4 bv4[NT];
    #pragma unroll
    for (int t = 0; t < NT; ++t) bv4[t] = *(const float4*)&bias[t * 16 + oct * 4];

    if constexpr (POOL) {
        // stage conv tile (bias added, bf16) into LDS [256 px][stride 40]
        __syncthreads();                                   // in_t reads complete
        #pragma unroll
        for (int r = 0; r < 4; ++r) {
            const int ly = wv * 4 + r;
            #pragma unroll
            for (int t = 0; t < NT; ++t) {
                uint2 o;
                o.x = pk2(acc[r][t][0] + bv4[t].x, acc[r][t][1] + bv4[t].y);
                o.y = pk2(acc[r][t][2] + bv4[t].z, acc[r][t][3] + bv4[t].w);
                *(uint2*)&in_t[(ly * 16 + col) * 40 + t * 16 + oct * 4] = o;
            }
        }
        __syncthreads();
        const int HP = H >> 1;
        const int py_lo = (ty0 == 0) ? 0 : (ty0 / 2 + 1);
        const int px_lo = (tx0 == 0) ? 0 : (tx0 / 2 + 1);
        const int ny = ty0 / 2 + 7 - py_lo + 1;
        const int nx = tx0 / 2 + 7 - px_lo + 1;
        constexpr int C8 = CO / 8;
        const int items = ny * nx * C8;
        for (int i = tid; i < items; i += 256) {
            const int c8 = i % C8; const int rr = i / C8;
            const int px = px_lo + rr % nx;
            const int py = py_lo + rr / nx;
            float m[8];
            #pragma unroll
            for (int k = 0; k < 8; ++k) m[k] = -FLT_MAX;
            #pragma unroll
            for (int wy = 0; wy < 3; ++wy) {
                const int gy = 2 * py - 1 + wy;
                if (gy < 0) continue;
                const int ly = gy - ty0;
                #pragma unroll
                for (int wx = 0; wx < 3; ++wx) {
                    const int gx = 2 * px - 1 + wx;
                    if (gx < 0) continue;
                    const int lx = gx - tx0;
                    const uint4 v = *(const uint4*)&in_t[(ly * 16 + lx) * 40 + c8 * 8];
                    m[0] = fmaxf(m[0], bflo_f(v.x)); m[1] = fmaxf(m[1], bfhi_f(v.x));
                    m[2] = fmaxf(m[2], bflo_f(v.y)); m[3] = fmaxf(m[3], bfhi_f(v.y));
                    m[4] = fmaxf(m[4], bflo_f(v.z)); m[5] = fmaxf(m[5], bfhi_f(v.z));
                    m[6] = fmaxf(m[6], bflo_f(v.w)); m[7] = fmaxf(m[7], bfhi_f(v.w));
                }
            }
            uint4 o;
            o.x = (unsigned)f2bf(m[0]) | ((unsigned)f2bf(m[1]) << 16);
            o.y = (unsigned)f2bf(m[2]) | ((unsigned)f2bf(m[3]) << 16);
            o.z = (unsigned)f2bf(m[4]) | ((unsigned)f2bf(m[5]) << 16);
            o.w = (unsigned)f2bf(m[6]) | ((unsigned)f2bf(m[7]) << 16);
            *(uint4*)&out[(((size_t)n * HP + py) * HP + px) * CO + c8 * 8] = o;
        }
    } else {
        #pragma unroll
        for (int r = 0; r < 4; ++r) {
            const int gy = ty0 + wv * 4 + r;
            const int gx = tx0 + col;
            const size_t pbase = (((size_t)n * H + gy) * H + gx) * CO + oct * 4;
            #pragma unroll
            for (int t = 0; t < NT; ++t) {
                float v0 = acc[r][t][0] + bv4[t].x;
                float v1 = acc[r][t][1] + bv4[t].y;
                float v2 = acc[r][t][2] + bv4[t].z;
                float v3 = acc[r][t][3] + bv4[t].w;
                if (skip) {
                    const uint2 s = *(const uint2*)&skip[pbase + t * 16];
                    v0 += bflo_f(s.x); v1 += bfhi_f(s.x);
                    v2 += bflo_f(s.y); v3 += bfhi_f(s.y);
                }
                uint2 o;
                o.x = pk2(v0, v1);
                o.y = pk2(v2, v3);
                *(uint2*)&out[pbase + t * 16] = o;
            }
        }
    }
}

// ---------------------------------------------------------------------------
// Split-K GEMM + reduce (fp32, unchanged)
// ---------------------------------------------------------------------------
__global__ __launch_bounds__(256) void gemm_splitk_k(
    const float* __restrict__ A, const float* __restrict__ B,
    float* __restrict__ partial, int M, int N, int K, int KC)
{
    __shared__ __align__(16) float As[32][65];
    __shared__ __align__(16) float Bs[32][65];
    const int m0 = blockIdx.x * 64, n0 = blockIdx.y * 64;
    const int kbase = blockIdx.z * KC;
    const int tid = threadIdx.x;
    const int tx = tid & 15, ty = tid >> 4;

    float acc[4][4];
    #pragma unroll
    for (int i = 0; i < 4; ++i)
        #pragma unroll
        for (int j = 0; j < 4; ++j) acc[i][j] = 0.f;

    for (int k0 = kbase; k0 < kbase + KC; k0 += 32) {
        for (int i = tid; i < 64 * 32; i += 256) {
            const int m = i >> 5, k = i & 31;
            As[k][m] = A[(size_t)(m0 + m) * K + k0 + k];
        }
        for (int i = tid; i < 64 * 32; i += 256) {
            const int nn = i >> 5, k = i & 31;
            Bs[k][nn] = B[(size_t)(n0 + nn) * K + k0 + k];
        }
        __syncthreads();
        #pragma unroll
        for (int k = 0; k < 32; ++k) {
            const float4 a = *(const float4*)&As[k][ty * 4];
            const float4 b = *(const float4*)&Bs[k][tx * 4];
            acc[0][0] = fmaf(a.x, b.x, acc[0][0]);
            acc[0][1] = fmaf(a.x, b.y, acc[0][1]);
            acc[0][2] = fmaf(a.x, b.z, acc[0][2]);
            acc[0][3] = fmaf(a.x, b.w, acc[0][3]);
            acc[1][0] = fmaf(a.y, b.x, acc[1][0]);
            acc[1][1] = fmaf(a.y, b.y, acc[1][1]);
            acc[1][2] = fmaf(a.y, b.z, acc[1][2]);
            acc[1][3] = fmaf(a.y, b.w, acc[1][3]);
            acc[2][0] = fmaf(a.z, b.x, acc[2][0]);
            acc[2][1] = fmaf(a.z, b.y, acc[2][1]);
            acc[2][2] = fmaf(a.z, b.z, acc[2][2]);
            acc[2][3] = fmaf(a.z, b.w, acc[2][3]);
            acc[3][0] = fmaf(a.w, b.x, acc[3][0]);
            acc[3][1] = fmaf(a.w, b.y, acc[3][1]);
            acc[3][2] = fmaf(a.w, b.z, acc[3][2]);
            acc[3][3] = fmaf(a.w, b.w, acc[3][3]);
        }
        __syncthreads();
    }

    float* pbase = partial + (size_t)blockIdx.z * M * N;
    #pragma unroll
    for (int i = 0; i < 4; ++i) {
        float4 o = make_float4(acc[i][0], acc[i][1], acc[i][2], acc[i][3]);
        *(float4*)&pbase[(size_t)(m0 + ty * 4 + i) * N + n0 + tx * 4] = o;
    }
}

__global__ __launch_bounds__(256) void gemm_reduce_k(
    const float* __restrict__ partial, const float* __restrict__ bias,
    float* __restrict__ out, int MN, int N, int S, int relu)
{
    const int idx = blockIdx.x * 256 + threadIdx.x;
    if (idx >= MN) return;
    float s = bias[idx % N];
    for (int i = 0; i < S; ++i) s += partial[(size_t)i * MN + idx];
    if (relu) s = fmaxf(s, 0.f);
    out[idx] = s;
}

// ---------------------------------------------------------------------------
// CBAM (leading relu): input NHWC bf16, output NCHW fp32  (unchanged)
// ---------------------------------------------------------------------------
__global__ __launch_bounds__(256) void cbam_k(
    const ushort_t* __restrict__ in, const float* __restrict__ fc1,
    const float* __restrict__ fc2, const float* __restrict__ spw,
    float* __restrict__ out)
{
    __shared__ float xl[32][257];
    __shared__ float cmean[32], cmax[32], hidm[8], hidx[8], ca[32];
    __shared__ float spm[256], spx[256], sa[256];
    const int n = blockIdx.x, tid = threadIdx.x;
    const ushort_t* inN = in + (size_t)n * 8192;
    #pragma unroll
    for (int c8 = 0; c8 < 4; ++c8) {
        const uint4 v = *(const uint4*)&inN[tid * 32 + c8 * 8];
        xl[c8 * 8 + 0][tid] = fmaxf(bflo_f(v.x), 0.f);
        xl[c8 * 8 + 1][tid] = fmaxf(bfhi_f(v.x), 0.f);
        xl[c8 * 8 + 2][tid] = fmaxf(bflo_f(v.y), 0.f);
        xl[c8 * 8 + 3][tid] = fmaxf(bfhi_f(v.y), 0.f);
        xl[c8 * 8 + 4][tid] = fmaxf(bflo_f(v.z), 0.f);
        xl[c8 * 8 + 5][tid] = fmaxf(bfhi_f(v.z), 0.f);
        xl[c8 * 8 + 6][tid] = fmaxf(bflo_f(v.w), 0.f);
        xl[c8 * 8 + 7][tid] = fmaxf(bfhi_f(v.w), 0.f);
    }
    __syncthreads();
    if (tid < 32) {
        float s = 0.f, m = -FLT_MAX;
        for (int p = 0; p < 256; ++p) { float v = xl[tid][p]; s += v; m = fmaxf(m, v); }
        cmean[tid] = s * (1.f / 256.f); cmax[tid] = m;
    }
    __syncthreads();
    if (tid < 8) {
        float sm = 0.f, sx = 0.f;
        for (int c = 0; c < 32; ++c) {
            float f = fc1[tid * 32 + c];
            sm += f * cmean[c]; sx += f * cmax[c];
        }
        hidm[tid] = fmaxf(sm, 0.f); hidx[tid] = fmaxf(sx, 0.f);
    }
    __syncthreads();
    if (tid < 32) {
        float s = 0.f;
        for (int h = 0; h < 8; ++h) s += fc2[tid * 8 + h] * (hidm[h] + hidx[h]);
        ca[tid] = 1.f / (1.f + expf(-s));
    }
    __syncthreads();
    {
        float s = 0.f, m = -FLT_MAX;
        for (int c = 0; c < 32; ++c) {
            float v = xl[c][tid] * ca[c];
            xl[c][tid] = v;
            s += v; m = fmaxf(m, v);
        }
        spm[tid] = s * (1.f / 32.f); spx[tid] = m;
    }
    __syncthreads();
    {
        const int y = tid >> 4, x = tid & 15;
        float s = 0.f;
        for (int ky = 0; ky < 7; ++ky) {
            const int yy = y + ky - 3;
            if (yy < 0 || yy >= 16) continue;
            for (int kx = 0; kx < 7; ++kx) {
                const int xx = x + kx - 3;
                if (xx < 0 || xx >= 16) continue;
                const int p = yy * 16 + xx;
                s += spm[p] * spw[ky * 7 + kx] + spx[p] * spw[49 + ky * 7 + kx];
            }
        }
        sa[tid] = 1.f / (1.f + expf(-s));
    }
    __syncthreads();
    float* outN = out + (size_t)n * 8192;
    const float sav = sa[tid];
    for (int c = 0; c < 32; ++c) outN[c * 256 + tid] = xl[c][tid] * sav;
}

// ---------------------------------------------------------------------------
// GRU scan: 2 barriers/step (done-mask folded linearly into gh)
// ---------------------------------------------------------------------------
__global__ __launch_bounds__(384) void gru_k(
    const float* __restrict__ gi, const float* __restrict__ done,
    const float* __restrict__ h0, const float* __restrict__ whh,
    const float* __restrict__ bhh, float* __restrict__ hidden)
{
    const int b = blockIdx.x, j = threadIdx.x;
    __shared__ __align__(16) float hl[128];
    __shared__ float gh[384];
    float4 wr[32];
    const float4* wrow = (const float4*)(whh + (size_t)j * 128);
    #pragma unroll
    for (int i = 0; i < 32; ++i) wr[i] = wrow[i];
    const float bj = bhh[j];
    if (j < 128) hl[j] = h0[b * 128 + j];
    __syncthreads();
    for (int t = 0; t < 64; ++t) {
        const int rowi = t * 8 + b;
        const float dmask = 1.f - done[rowi];
        float s = 0.f;
        const float4* h4 = (const float4*)hl;
        #pragma unroll
        for (int i = 0; i < 32; ++i) {
            const float4 h = h4[i];
            s = fmaf(wr[i].x, h.x, s);
            s = fmaf(wr[i].y, h.y, s);
            s = fmaf(wr[i].z, h.z, s);
            s = fmaf(wr[i].w, h.w, s);
        }
        gh[j] = fmaf(s, dmask, bj);     // = whh·(dmask*h) + bhh  (dmask ∈ {0,1})
        __syncthreads();
        if (j < 128) {
            const float* gir = gi + (size_t)rowi * 384;
            const float r = 1.f / (1.f + expf(-(gir[j] + gh[j])));
            const float z = 1.f / (1.f + expf(-(gir[128 + j] + gh[128 + j])));
            const float nn = tanhf(gir[256 + j] + r * gh[256 + j]);
            const float hm = hl[j] * dmask;
            const float hn = (1.f - z) * nn + z * hm;
            hl[j] = hn;
            hidden[(size_t)rowi * 128 + j] = hn;
        }
        __syncthreads();
    }
}

// ---------------------------------------------------------------------------
// actor/critic heads (unchanged)
// ---------------------------------------------------------------------------
__global__ __launch_bounds__(256) void heads_k(
    const float* __restrict__ hidden, const float* __restrict__ aw,
    const float* __restrict__ ab, const float* __restrict__ cw,
    const float* __restrict__ cb, float* __restrict__ out)
{
    const int idx = blockIdx.x * 256 + threadIdx.x;  // 2048
    const int m = idx >> 2, c = idx & 3;
    const float* h = hidden + (size_t)m * 128;
    const float* w = (c < 3) ? (aw + (size_t)c * 128) : cw;
    float s = (c < 3) ? ab[c] : cb[0];
    for (int k = 0; k < 128; ++k) s = fmaf(h[k], w[k], s);
    out[idx] = s;
}

// ---------------------------------------------------------------------------
extern "C" void kernel_launch(void* const* d_in, const int* in_sizes, int n_in,
                              void* d_out, int out_size, void* d_ws, size_t ws_size,
                              hipStream_t stream)
{
    const float* x      = (const float*)d_in[0];
    const float* done   = (const float*)d_in[1];
    const float* gstate = (const float*)d_in[2];
    const float* s0_cw  = (const float*)d_in[3];
    const float* s0_cb  = (const float*)d_in[4];
    const float* s0_rw  = (const float*)d_in[5];
    const float* s0_rb  = (const float*)d_in[6];
    const float* s1_cw  = (const float*)d_in[7];
    const float* s1_cb  = (const float*)d_in[8];
    const float* s1_rw  = (const float*)d_in[9];
    const float* s1_rb  = (const float*)d_in[10];
    const float* s2_cw  = (const float*)d_in[11];
    const float* s2_cb  = (const float*)d_in[12];
    const float* s2_rw  = (const float*)d_in[13];
    const float* s2_rb  = (const float*)d_in[14];
    const float* cfc1   = (const float*)d_in[15];
    const float* cfc2   = (const float*)d_in[16];
    const float* cspw   = (const float*)d_in[17];
    const float* fc_w   = (const float*)d_in[18];
    const float* fc_b   = (const float*)d_in[19];
    const float* gwih   = (const float*)d_in[20];
    const float* gwhh   = (const float*)d_in[21];
    const float* gbih   = (const float*)d_in[22];
    const float* gbhh   = (const float*)d_in[23];
    const float* aw     = (const float*)d_in[24];
    const float* ab     = (const float*)d_in[25];
    const float* cwt    = (const float*)d_in[26];
    const float* cbs    = (const float*)d_in[27];
    float* out = (float*)d_out;

    // ---- ws layout (ushort units) ----
    ushort_t* wsu = (ushort_t*)d_ws;
    ushort_t* SCR = wsu;                       // 33,554,432 u (67.1 MB) resblock temp
    ushort_t* U1  = wsu + 33554432;            // 33,554,432 u (67.1 MB) s0 x
    ushort_t* U3  = wsu + 67108864;            // 16,777,216 u (33.5 MB) s1 x
    ushort_t* X0  = wsu + 83886080;            //  4,194,304 u ( 8.4 MB) s2 x
    ushort_t* WP  = wsu + 88080384;            //    131,072 u  weights
    // fp32 misc (placed in U1 region, free by FC time); CBO in SCR region
    float* CBO   = (float*)SCR;                // 4,194,304 f
    float* PART  = (float*)U1;                 // 4,194,304 f
    float* FEAT  = PART + 4194304;             //   131,072 f
    float* GI    = FEAT + 131072;              //   196,608 f
    float* PARTG = GI + 196608;                //   786,432 f
    float* HID   = PARTG + 786432;             //    65,536 f

    // ---- prepack all 15 conv weight tensors (packed-K layout) ----
    ushort_t* wp_s0e = WP;                       // 1536
    ushort_t* wp_s0r = WP + 1536;                // 4 x 3072
    ushort_t* wp_s1e = WP + 13824;               // 6144
    ushort_t* wp_s1r = WP + 19968;               // 4 x 9216
    ushort_t* wp_s2e = WP + 56832;               // 9216
    ushort_t* wp_s2r = WP + 66048;               // 4 x 9216 -> end 102912
    {
        PPArgs a;
        a.j[0] = {s0_cw, wp_s0e, 6, 16, 1};
        for (int i = 0; i < 4; ++i) a.j[1 + i] = {s0_rw + i * 2304, wp_s0r + i * 3072, 16, 16, 2};
        a.j[5] = {s1_cw, wp_s1e, 16, 32, 2};
        for (int i = 0; i < 4; ++i) a.j[6 + i] = {s1_rw + i * 9216, wp_s1r + i * 9216, 32, 32, 4};
        a.j[10] = {s2_cw, wp_s2e, 32, 32, 4};
        for (int i = 0; i < 4; ++i) a.j[11 + i] = {s2_rw + i * 9216, wp_s2r + i * 9216, 32, 32, 4};
        prepack_k<<<15, 256, 0, stream>>>(a);
    }

    // ---- stage 0: fused entry conv (6->16 @128) + maxpool -> U1 (@64) ----
    convm_k<6, 16, true, true><<<dim3(81, 512), 256, 0, stream>>>(
        x, wp_s0e, s0_cb, nullptr, U1, 128, 9, 0);
    // ---- stage 0 resblocks (16ch @64) ----
    convm_k<16, 16, false, false><<<dim3(16, 512), 256, 0, stream>>>(U1,  wp_s0r + 0 * 3072, s0_rb + 0,  nullptr, SCR, 64, 4, 1);
    convm_k<16, 16, false, false><<<dim3(16, 512), 256, 0, stream>>>(SCR, wp_s0r + 1 * 3072, s0_rb + 16, U1,      U1,  64, 4, 1);
    convm_k<16, 16, false, false><<<dim3(16, 512), 256, 0, stream>>>(U1,  wp_s0r + 2 * 3072, s0_rb + 32, nullptr, SCR, 64, 4, 1);
    convm_k<16, 16, false, false><<<dim3(16, 512), 256, 0, stream>>>(SCR, wp_s0r + 3 * 3072, s0_rb + 48, U1,      U1,  64, 4, 1);
    // ---- stage 1: fused entry conv (16->32 @64) + maxpool -> U3 (@32) ----
    convm_k<16, 32, false, true><<<dim3(25, 512), 256, 0, stream>>>(
        U1, wp_s1e, s1_cb, nullptr, U3, 64, 5, 0);
    // ---- stage 1 resblocks (32ch @32) ----
    convm_k<32, 32, false, false><<<dim3(4, 512), 256, 0, stream>>>(U3,  wp_s1r + 0 * 9216, s1_rb + 0,  nullptr, SCR, 32, 2, 1);
    convm_k<32, 32, false, false><<<dim3(4, 512), 256, 0, stream>>>(SCR, wp_s1r + 1 * 9216, s1_rb + 32, U3,      U3,  32, 2, 1);
    convm_k<32, 32, false, false><<<dim3(4, 512), 256, 0, stream>>>(U3,  wp_s1r + 2 * 9216, s1_rb + 64, nullptr, SCR, 32, 2, 1);
    convm_k<32, 32, false, false><<<dim3(4, 512), 256, 0, stream>>>(SCR, wp_s1r + 3 * 9216, s1_rb + 96, U3,      U3,  32, 2, 1);
    // ---- stage 2: fused entry conv (32->32 @32) + maxpool -> X0 (@16) ----
    convm_k<32, 32, false, true><<<dim3(9, 512), 256, 0, stream>>>(
        U3, wp_s2e, s2_cb, nullptr, X0, 32, 3, 0);
    // ---- stage 2 resblocks (32ch @16) ----
    convm_k<32, 32, false, false><<<dim3(1, 512), 256, 0, stream>>>(X0,  wp_s2r + 0 * 9216, s2_rb + 0,  nullptr, SCR, 16, 1, 1);
    convm_k<32, 32, false, false><<<dim3(1, 512), 256, 0, stream>>>(SCR, wp_s2r + 1 * 9216, s2_rb + 32, X0,      X0,  16, 1, 1);
    convm_k<32, 32, false, false><<<dim3(1, 512), 256, 0, stream>>>(X0,  wp_s2r + 2 * 9216, s2_rb + 64, nullptr, SCR, 16, 1, 1);
    convm_k<32, 32, false, false><<<dim3(1, 512), 256, 0, stream>>>(SCR, wp_s2r + 3 * 9216, s2_rb + 96, X0,      X0,  16, 1, 1);
    // ---- relu + CBAM (NHWC bf16 -> NCHW fp32) ----
    cbam_k<<<512, 256, 0, stream>>>(X0, cfc1, cfc2, cspw, CBO);
    // ---- FC 8192->256 (+relu), split-K=32 ----
    gemm_splitk_k<<<dim3(8, 4, 32), 256, 0, stream>>>(CBO, fc_w, PART, 512, 256, 8192, 256);
    gemm_reduce_k<<<512, 256, 0, stream>>>(PART, fc_b, FEAT, 512 * 256, 256, 32, 1);
    // ---- gi = feat @ Wih^T + bih, split-K=4 ----
    gemm_splitk_k<<<dim3(8, 6, 4), 256, 0, stream>>>(FEAT, gwih, PARTG, 512, 384, 256, 64);
    gemm_reduce_k<<<768, 256, 0, stream>>>(PARTG, gbih, GI, 512 * 384, 384, 4, 0);
    // ---- GRU scan ----
    gru_k<<<8, 384, 0, stream>>>(GI, done, gstate, gwhh, gbhh, HID);
    // ---- heads ----
    heads_k<<<8, 256, 0, stream>>>(HID, aw, ab, cwt, cbs, out);
}